// Round 1
// baseline (35.709 us; speedup 1.0000x reference)
//
#include <hip/hip_runtime.h>
#include <math.h>

#define NFFT   512
#define NSPEC  257
#define NFILT  40
#define FLEN   25      // frame_length = round(0.025*1000)
#define FSTEP  10      // frame_step   = round(0.010*1000)
#define BATCH  32
#define SIGLEN 50000
#define NFRAMES 4999   // ceil((50000-25)/10)+1
#define EPSV   2.220446049250313e-16f

// ---------------- kernel 1: build C[f][d] table from fs ----------------
// C[f][d] = (d==0 ? 1 : 2)/512 * sum_k fbank[f][k] * cos(2*pi*k*d/512)
__global__ void build_C(const int* __restrict__ fs_p, float* __restrict__ C) {
    int idx = blockIdx.x * blockDim.x + threadIdx.x;
    if (idx >= NFILT * FLEN) return;
    int f = idx / FLEN;   // filter index 0..39
    int d = idx % FLEN;   // lag 0..24

    double fs = (double)fs_p[0];
    double high_mel = 2595.0 * log10(1.0 + fs / 2.0 / 700.0);

    // b[i] for i = f, f+1, f+2  (mel_points = linspace(0, high, NFILT+2))
    double bv[3];
    #pragma unroll
    for (int j = 0; j < 3; ++j) {
        double mel = high_mel * (double)(f + j) / (double)(NFILT + 1);
        double hz  = 700.0 * (pow(10.0, mel / 2595.0) - 1.0);
        bv[j] = hz / (fs / 2.0) * ((double)NFFT / 2.0);
    }
    int left   = (int)bv[0];
    int center = (int)bv[1];
    int right  = (int)bv[2];

    double acc = 0.0;
    for (int j = left; j < right; ++j) {
        double w = (j < center) ? ((double)(j + 1) - bv[0]) / (bv[1] - bv[0])
                                : (bv[2] - (double)(j + 1)) / (bv[2] - bv[1]);
        int k = j + 1;                       // spectral bin, 1..256
        // cos(2*pi*k*d/512) = cospi(k*d/256)
        acc += w * cospi((double)(k * d) / 256.0);
    }
    double val = acc / (double)NFFT;
    if (d > 0) val *= 2.0;
    C[idx] = (float)val;
}

// ---------------- kernel 2: main mel-filterbank kernel ----------------
// One thread per frame. Block = 256 consecutive frames of one batch row.
#define TPB 256
#define SPAN (TPB * FSTEP + FLEN - FSTEP)   // 2575 samples touched per block
#define SPAN4 2576                          // padded to float4 multiple

__global__ __launch_bounds__(TPB) void mel_main(const float* __restrict__ sig,
                                                const float* __restrict__ C,
                                                float* __restrict__ out) {
    const int b   = blockIdx.y;
    const int t0  = blockIdx.x * TPB;       // first frame handled by block
    const int tid = threadIdx.x;
    const int t   = t0 + tid;

    __shared__ float s_sig[SPAN4];

    // ---- stage signal window [t0*FSTEP, t0*FSTEP + SPAN) into LDS ----
    const int base = t0 * FSTEP;
    const int rem  = SIGLEN - base;          // valid elements from base
    const float* sb = sig + (size_t)b * SIGLEN + base;
    for (int i = tid * 4; i < SPAN4; i += TPB * 4) {
        float4 v = make_float4(0.f, 0.f, 0.f, 0.f);
        if (i + 4 <= rem) {
            v = *reinterpret_cast<const float4*>(sb + i);
        } else if (i < rem) {
            v.x = sb[i];
            if (i + 1 < rem) v.y = sb[i + 1];
            if (i + 2 < rem) v.z = sb[i + 2];
        }
        *reinterpret_cast<float4*>(s_sig + i) = v;
    }
    __syncthreads();

    if (t >= NFRAMES) return;

    // ---- load this thread's 25 samples ----
    float x[FLEN];
    const float* sp = s_sig + tid * FSTEP;
    #pragma unroll
    for (int n = 0; n < FLEN; ++n) x[n] = sp[n];

    // ---- autocorrelation R[d] = sum_n x[n]*x[n+d] ----
    float R[FLEN];
    #pragma unroll
    for (int d = 0; d < FLEN; ++d) {
        float acc = 0.f;
        #pragma unroll
        for (int n = 0; n + d < FLEN; ++n) acc = fmaf(x[n], x[n + d], acc);
        R[d] = acc;
    }

    // ---- fb[f] = C[f] . R ; out = 20*log10(fb) ----
    float fbv[NFILT];
    #pragma unroll
    for (int f = 0; f < NFILT; ++f) {
        float acc = 0.f;
        #pragma unroll
        for (int d = 0; d < FLEN; ++d) acc = fmaf(C[f * FLEN + d], R[d], acc);
        if (acc < EPSV) acc = EPSV;          // matches where(fb==0, EPS, fb)
        // 20*log10(v) = 20/log2(10) * log2(v)
        fbv[f] = 6.0205999132796239f * __log2f(acc);
    }

    float* op = out + ((size_t)b * NFRAMES + t) * NFILT;
    #pragma unroll
    for (int q = 0; q < NFILT / 4; ++q) {
        *reinterpret_cast<float4*>(op + q * 4) =
            make_float4(fbv[q * 4], fbv[q * 4 + 1], fbv[q * 4 + 2], fbv[q * 4 + 3]);
    }
}

extern "C" void kernel_launch(void* const* d_in, const int* in_sizes, int n_in,
                              void* d_out, int out_size, void* d_ws, size_t ws_size,
                              hipStream_t stream) {
    const float* sig = (const float*)d_in[0];
    const int*   fs  = (const int*)d_in[1];
    float* out = (float*)d_out;
    float* C   = (float*)d_ws;               // NFILT*FLEN floats = 4 KB

    build_C<<<dim3(4), dim3(256), 0, stream>>>(fs, C);

    dim3 grid((NFRAMES + TPB - 1) / TPB, BATCH);
    mel_main<<<grid, dim3(TPB), 0, stream>>>(sig, C, out);
}

// Round 2
// 35.087 us; speedup vs baseline: 1.0177x; 1.0177x over previous
//
#include <hip/hip_runtime.h>
#include <math.h>

#define NFILT   40
#define FLEN    25      // frame_length = round(0.025*1000)
#define FPAD    28      // FLEN padded to float4 multiple
#define FSTEP   10      // frame_step = round(0.010*1000)
#define BATCH   32
#define SIGLEN  50000
#define NFRAMES 4999    // ceil((50000-25)/10)+1
#define EPSV    2.220446049250313e-16f
#define TPB     256
#define SPAN4   2576    // (TPB*FSTEP + FLEN - FSTEP) = 2575, padded to x4

// Single fused kernel:
//  fb[t][f] = sum_d C[f][d] * R[t][d],  R[t][d] = in-frame autocorrelation,
//  C[f][d]  = (d==0?1:2)/512 * sum_k fbank[f][k]*cos(2*pi*k*d/512)
// C is built per-block in LDS (boundaries in double for exact int() bins,
// cosine sum in float), signal window staged in LDS, matvec via float4
// LDS broadcasts with filters processed 4 at a time (small live state).
__global__ __launch_bounds__(TPB) void mel_fused(const float* __restrict__ sig,
                                                 const int* __restrict__ fs_p,
                                                 float* __restrict__ out) {
    const int b   = blockIdx.y;
    const int t0  = blockIdx.x * TPB;
    const int tid = threadIdx.x;
    const int t   = t0 + tid;

    __shared__ double s_b[NFILT + 2];
    __shared__ float  s_C[NFILT * FPAD];
    __shared__ float  s_sig[SPAN4];

    // ---- stage signal window [t0*FSTEP, t0*FSTEP+SPAN) into LDS ----
    const int base = t0 * FSTEP;
    const int rem  = SIGLEN - base;
    const float* sb = sig + (size_t)b * SIGLEN + base;
    for (int i = tid * 4; i < SPAN4; i += TPB * 4) {
        float4 v = make_float4(0.f, 0.f, 0.f, 0.f);
        if (i + 4 <= rem) {
            v = *reinterpret_cast<const float4*>(sb + i);
        } else if (i < rem) {
            v.x = sb[i];
            if (i + 1 < rem) v.y = sb[i + 1];
            if (i + 2 < rem) v.z = sb[i + 2];
        }
        *reinterpret_cast<float4*>(s_sig + i) = v;
    }

    // ---- mel boundary points b[i], exact in double (bin truncation!) ----
    if (tid < NFILT + 2) {
        double fs = (double)fs_p[0];
        double high_mel = 2595.0 * log10(1.0 + fs * (0.5 / 700.0));
        double mel = high_mel * (double)tid / (double)(NFILT + 1);
        // 10^(mel/2595) = exp2(mel/2595 * log2(10))
        double hz  = 700.0 * (exp2(mel * (3.321928094887362 / 2595.0)) - 1.0);
        s_b[tid] = hz * (512.0 / fs);      // hz/(fs/2) * (nfft/2)
    }
    __syncthreads();

    // ---- C table: 40 filters x 28 lags (pad lags 25..27 with 0) ----
    for (int idx = tid; idx < NFILT * FPAD; idx += TPB) {
        int f = idx / FPAD;
        int d = idx % FPAD;
        float val = 0.f;
        if (d < FLEN) {
            double bl = s_b[f], bc = s_b[f + 1], br = s_b[f + 2];
            int left = (int)bl, center = (int)bc, right = (int)br;
            float acc = 0.f;
            for (int j = left; j < right; ++j) {
                double w = (j < center) ? ((double)(j + 1) - bl) / (bc - bl)
                                        : (br - (double)(j + 1)) / (br - bc);
                int m = ((j + 1) * d) & 511;               // k*d mod 512
                acc = fmaf((float)w, __cosf((float)m * 0.012271846303085130f), acc);
            }
            val = acc * (d ? (2.0f / 512.0f) : (1.0f / 512.0f));
        }
        s_C[idx] = val;
    }
    __syncthreads();

    if (t >= NFRAMES) return;

    // ---- this frame's 25 samples ----
    float x[FLEN];
    const float* sp = s_sig + tid * FSTEP;
    #pragma unroll
    for (int n = 0; n < FLEN; ++n) x[n] = sp[n];

    // ---- autocorrelation R[d] = sum_n x[n]*x[n+d] ----
    float R[FPAD];
    #pragma unroll
    for (int d = 0; d < FLEN; ++d) {
        float a = 0.f;
        #pragma unroll
        for (int n = 0; n + d < FLEN; ++n) a = fmaf(x[n], x[n + d], a);
        R[d] = a;
    }
    #pragma unroll
    for (int d = FLEN; d < FPAD; ++d) R[d] = 0.f;

    // ---- 4 filters at a time: dot(C_row, R) -> clamp -> 20*log10 -> store ----
    float* op = out + ((size_t)b * NFRAMES + t) * NFILT;
    #pragma unroll
    for (int fq = 0; fq < NFILT / 4; ++fq) {
        float acc[4];
        #pragma unroll
        for (int s = 0; s < 4; ++s) {
            const float4* cp = reinterpret_cast<const float4*>(s_C + (fq * 4 + s) * FPAD);
            float a = 0.f;
            #pragma unroll
            for (int q = 0; q < FPAD / 4; ++q) {
                float4 c = cp[q];
                a = fmaf(c.x, R[q * 4 + 0], a);
                a = fmaf(c.y, R[q * 4 + 1], a);
                a = fmaf(c.z, R[q * 4 + 2], a);
                a = fmaf(c.w, R[q * 4 + 3], a);
            }
            if (a < EPSV) a = EPSV;
            acc[s] = 6.0205999132796239f * __log2f(a);   // 20*log10
        }
        *reinterpret_cast<float4*>(op + fq * 4) =
            make_float4(acc[0], acc[1], acc[2], acc[3]);
    }
}

extern "C" void kernel_launch(void* const* d_in, const int* in_sizes, int n_in,
                              void* d_out, int out_size, void* d_ws, size_t ws_size,
                              hipStream_t stream) {
    const float* sig = (const float*)d_in[0];
    const int*   fs  = (const int*)d_in[1];
    float* out = (float*)d_out;

    dim3 grid((NFRAMES + TPB - 1) / TPB, BATCH);
    mel_fused<<<grid, dim3(TPB), 0, stream>>>(sig, fs, out);
}

// Round 3
// 33.023 us; speedup vs baseline: 1.0814x; 1.0625x over previous
//
#include <hip/hip_runtime.h>
#include <math.h>

#define NFILT   40
#define FLEN    25      // frame_length = round(0.025*1000)
#define FPAD    28      // FLEN padded to float4 multiple
#define FSTEP   10      // frame_step = round(0.010*1000)
#define BATCH   32
#define SIGLEN  50000
#define NFRAMES 4999    // ceil((50000-25)/10)+1
#define EPSV    2.220446049250313e-16f
#define TPB     256
#define SPAN4   2576    // (TPB*FSTEP + FLEN - FSTEP) = 2575, padded to x4
#define OSTRIDE 41      // padded LDS stride for the output transpose

__global__ __launch_bounds__(TPB) void mel_fused(const float* __restrict__ sig,
                                                 const int* __restrict__ fs_p,
                                                 float* __restrict__ out) {
    const int b   = blockIdx.y;
    const int t0  = blockIdx.x * TPB;
    const int tid = threadIdx.x;

    __shared__ double s_b[NFILT + 2];
    __shared__ float  s_C[NFILT * FPAD];
    __shared__ float  s_sig[SPAN4];
    __shared__ float  s_stage[64 * OSTRIDE];   // 64 frames x 40 filters, padded

    // ---- stage signal window [t0*FSTEP, t0*FSTEP+SPAN) into LDS ----
    const int base = t0 * FSTEP;
    const int rem  = SIGLEN - base;
    const float* sb = sig + (size_t)b * SIGLEN + base;
    for (int i = tid * 4; i < SPAN4; i += TPB * 4) {
        float4 v = make_float4(0.f, 0.f, 0.f, 0.f);
        if (i + 4 <= rem) {
            v = *reinterpret_cast<const float4*>(sb + i);
        } else if (i < rem) {
            v.x = sb[i];
            if (i + 1 < rem) v.y = sb[i + 1];
            if (i + 2 < rem) v.z = sb[i + 2];
        }
        *reinterpret_cast<float4*>(s_sig + i) = v;
    }

    // ---- mel boundary points b[i], exact in double (bin truncation!) ----
    if (tid < NFILT + 2) {
        double fs = (double)fs_p[0];
        double high_mel = 2595.0 * log10(1.0 + fs * (0.5 / 700.0));
        double mel = high_mel * (double)tid / (double)(NFILT + 1);
        double hz  = 700.0 * (exp2(mel * (3.321928094887362 / 2595.0)) - 1.0);
        s_b[tid] = hz * (512.0 / fs);      // hz/(fs/2) * (nfft/2)
    }
    __syncthreads();

    // ---- C table: 40 filters x 28 lags; float inner loop, hoisted divides ----
    for (int idx = tid; idx < NFILT * FPAD; idx += TPB) {
        int f = idx / FPAD;
        int d = idx % FPAD;
        float val = 0.f;
        if (d < FLEN) {
            double bl = s_b[f], bc = s_b[f + 1], br = s_b[f + 2];
            int left = (int)bl, center = (int)bc, right = (int)br;
            float blf = (float)bl, bcf = (float)bc, brf = (float)br;
            float invA = 1.0f / (bcf - blf);
            float invB = 1.0f / (brf - bcf);
            float acc = 0.f;
            for (int j = left; j < right; ++j) {
                float jp1 = (float)(j + 1);
                float w = (j < center) ? (jp1 - blf) * invA : (brf - jp1) * invB;
                int m = ((j + 1) * d) & 511;               // k*d mod 512
                acc = fmaf(w, __cosf((float)m * 0.012271846303085130f), acc);
            }
            val = acc * (d ? (2.0f / 512.0f) : (1.0f / 512.0f));
        }
        s_C[idx] = val;
    }
    __syncthreads();

    // ---- this frame's 25 samples (always in-bounds; zero-padded tail) ----
    float x[FLEN];
    const float* sp = s_sig + tid * FSTEP;
    #pragma unroll
    for (int n = 0; n < FLEN; ++n) x[n] = sp[n];

    // ---- autocorrelation R[d] = sum_n x[n]*x[n+d] ----
    float R[FPAD];
    #pragma unroll
    for (int d = 0; d < FLEN; ++d) {
        float a = 0.f;
        #pragma unroll
        for (int n = 0; n + d < FLEN; ++n) a = fmaf(x[n], x[n + d], a);
        R[d] = a;
    }
    #pragma unroll
    for (int d = FLEN; d < FPAD; ++d) R[d] = 0.f;

    // ---- all 40 filters: dot(C_row, R) -> clamp -> 20*log10 (keep in regs) ----
    float fbv[NFILT];
    #pragma unroll
    for (int f = 0; f < NFILT; ++f) {
        const float4* cp = reinterpret_cast<const float4*>(s_C + f * FPAD);
        float a = 0.f;
        #pragma unroll
        for (int q = 0; q < FPAD / 4; ++q) {
            float4 c = cp[q];
            a = fmaf(c.x, R[q * 4 + 0], a);
            a = fmaf(c.y, R[q * 4 + 1], a);
            a = fmaf(c.z, R[q * 4 + 2], a);
            a = fmaf(c.w, R[q * 4 + 3], a);
        }
        if (a < EPSV) a = EPSV;
        fbv[f] = 6.0205999132796239f * __log2f(a);   // 20*log10
    }

    // ---- output transpose: 4 rounds of 64 frames; coalesced stores ----
    const size_t outbase = ((size_t)b * NFRAMES + t0) * NFILT;
    #pragma unroll 1
    for (int g = 0; g < 4; ++g) {
        __syncthreads();                       // protect s_stage reuse
        if ((tid >> 6) == g) {                 // wave-uniform branch
            int lt = tid & 63;
            #pragma unroll
            for (int f = 0; f < NFILT; ++f)
                s_stage[lt * OSTRIDE + f] = fbv[f];
        }
        __syncthreads();
        // flat chunk: frames [t0+g*64, t0+g*64+64) x 40 filters = 2560 floats
        #pragma unroll
        for (int j = 0; j < 10; ++j) {
            int i  = j * TPB + tid;            // 0..2559, lane-consecutive
            int tl = i / 40;
            int f  = i - tl * 40;
            int tglob = t0 + g * 64 + tl;
            if (tglob < NFRAMES)
                out[outbase + (size_t)g * 2560 + i] = s_stage[tl * OSTRIDE + f];
        }
    }
}

extern "C" void kernel_launch(void* const* d_in, const int* in_sizes, int n_in,
                              void* d_out, int out_size, void* d_ws, size_t ws_size,
                              hipStream_t stream) {
    const float* sig = (const float*)d_in[0];
    const int*   fs  = (const int*)d_in[1];
    float* out = (float*)d_out;

    dim3 grid((NFRAMES + TPB - 1) / TPB, BATCH);
    mel_fused<<<grid, dim3(TPB), 0, stream>>>(sig, fs, out);
}

// Round 4
// 20.011 us; speedup vs baseline: 1.7845x; 1.6502x over previous
//
#include <hip/hip_runtime.h>

#define NFILT   40
#define FLEN    25      // frame_length = round(0.025*1000)
#define FSTEP   10      // frame_step = round(0.010*1000)
#define BATCH   32
#define SIGLEN  50000
#define NFRAMES 4999    // ceil((50000-25)/10)+1
#define EPSV    2.220446049250313e-16f
#define TPB     256
#define SPAN4   2576    // (TPB*FSTEP + FLEN - FSTEP)=2575, padded to x4
#define OSTR    41      // LDS transpose stride (odd => 2-way bank aliasing, free)

namespace ctab {

constexpr double PI   = 3.14159265358979323846264338327950288;
constexpr double LN10 = 2.30258509299404568401799145468436421;

constexpr double cln(double y) {            // natural log near 1.7 (atanh series)
    double z = (y - 1.0) / (y + 1.0);
    double z2 = z * z, term = z, s = 0.0;
    for (int k = 0; k < 40; ++k) { s += term / (2.0 * k + 1.0); term *= z2; }
    return 2.0 * s;
}
constexpr double cexp(double x) {           // exp, |x| < 0.6
    double s = 1.0, term = 1.0;
    for (int i = 1; i <= 24; ++i) { term *= x / (double)i; s += term; }
    return s;
}
constexpr double ccospi_r(double t) {       // cos(pi*t), t in [0,0.5]
    double x = PI * t, x2 = x * x;
    double s = 1.0, term = 1.0;
    for (int k = 1; k <= 16; ++k) { term *= -x2 / ((2.0 * k - 1.0) * (2.0 * k)); s += term; }
    return s;
}
constexpr double ccospi_m(int m) {          // cos(pi * m / 256), any m >= 0
    int mm = m & 511;
    if (mm > 256) mm = 512 - mm;            // cos(2pi - x) = cos(x)
    if (mm <= 128) return ccospi_r(mm / 256.0);
    return -ccospi_r((256 - mm) / 256.0);   // cos(pi - x) = -cos(x)
}

// C[f][d] = (d==0?1:2)/512 * sum_k fbank[f][k] * cos(2*pi*k*d/512)
// fs = 1000 (the kernel is already fs-specialized: FLEN/FSTEP/NFRAMES).
struct CTab {
    float c[NFILT][FLEN];
    constexpr CTab() : c{} {
        double ct[512] = {};
        for (int m = 0; m < 512; ++m) ct[m] = ccospi_m(m);
        double fs = 1000.0;
        double high_mel = 2595.0 * (cln(1.0 + fs / 2.0 / 700.0) / LN10);
        double b[NFILT + 2] = {};
        for (int i = 0; i < NFILT + 2; ++i) {
            double mel = high_mel * (double)i / (double)(NFILT + 1);
            double hz  = 700.0 * (cexp(mel / 2595.0 * LN10) - 1.0);
            b[i] = hz / (fs / 2.0) * 256.0;         // hz/(fs/2) * (nfft/2)
        }
        for (int f = 0; f < NFILT; ++f) {
            int left = (int)b[f], center = (int)b[f + 1], right = (int)b[f + 2];
            for (int d = 0; d < FLEN; ++d) {
                double acc = 0.0;
                for (int j = left; j < right; ++j) {
                    double w = (j < center)
                        ? ((double)(j + 1) - b[f])     / (b[f + 1] - b[f])
                        : (b[f + 2] - (double)(j + 1)) / (b[f + 2] - b[f + 1]);
                    acc += w * ct[((j + 1) * d) & 511];
                }
                double v = acc / 512.0;
                if (d) v *= 2.0;
                c[f][d] = (float)v;
            }
        }
    }
};
static constexpr CTab CT{};

} // namespace ctab

__global__ __launch_bounds__(TPB) void mel_main(const float* __restrict__ sig,
                                                float* __restrict__ out) {
    const int b   = blockIdx.y;
    const int t0  = blockIdx.x * TPB;
    const int tid = threadIdx.x;

    __shared__ float s_sig[SPAN4];
    __shared__ float s_stage[128 * OSTR];

    // ---- stage signal window [t0*FSTEP, t0*FSTEP+SPAN) into LDS ----
    const int base = t0 * FSTEP;
    const int rem  = SIGLEN - base;
    const float* sb = sig + (size_t)b * SIGLEN + base;
    for (int i = tid * 4; i < SPAN4; i += TPB * 4) {
        float4 v = make_float4(0.f, 0.f, 0.f, 0.f);
        if (i + 4 <= rem) {
            v = *reinterpret_cast<const float4*>(sb + i);
        } else if (i < rem) {
            v.x = sb[i];
            if (i + 1 < rem) v.y = sb[i + 1];
            if (i + 2 < rem) v.z = sb[i + 2];
        }
        *reinterpret_cast<float4*>(s_sig + i) = v;
    }
    __syncthreads();

    // ---- this frame's 25 samples (zero-padded tail matches reference pad) ----
    float x[FLEN];
    const float* sp = s_sig + tid * FSTEP;
    #pragma unroll
    for (int n = 0; n < FLEN; ++n) x[n] = sp[n];

    // ---- autocorrelation R[d] = sum_n x[n]*x[n+d] ----
    float R[FLEN];
    #pragma unroll
    for (int d = 0; d < FLEN; ++d) {
        float a = 0.f;
        #pragma unroll
        for (int n = 0; n + d < FLEN; ++n) a = fmaf(x[n], x[n + d], a);
        R[d] = a;
    }

    // ---- fb[f] = C[f].R with C as instruction literals; 20*log10 ----
    float fbv[NFILT];
    #pragma unroll
    for (int f = 0; f < NFILT; ++f) {
        float a = 0.f;
        #pragma unroll
        for (int d = 0; d < FLEN; ++d)
            a = fmaf(ctab::CT.c[f][d], R[d], a);
        if (a < EPSV) a = EPSV;
        fbv[f] = 6.0205999132796239f * __log2f(a);   // 20*log10
    }

    // ---- output transpose: 2 rounds of 128 frames; coalesced stores ----
    const size_t outbase = ((size_t)b * NFRAMES + t0) * NFILT;
    #pragma unroll 1
    for (int r = 0; r < 2; ++r) {
        __syncthreads();
        if ((tid >> 7) == r) {                  // wave-uniform (128 = 2 waves)
            int lt = tid & 127;
            #pragma unroll
            for (int f = 0; f < NFILT; ++f)
                s_stage[lt * OSTR + f] = fbv[f];
        }
        __syncthreads();
        const int f0 = t0 + r * 128;
        #pragma unroll
        for (int j = 0; j < 20; ++j) {
            int i  = j * TPB + tid;             // 0..5119, lane-consecutive
            int fr = i / 40;
            int fl = i - fr * 40;
            if (f0 + fr < NFRAMES)
                out[outbase + (size_t)r * (128 * NFILT) + i] = s_stage[fr * OSTR + fl];
        }
    }
}

extern "C" void kernel_launch(void* const* d_in, const int* in_sizes, int n_in,
                              void* d_out, int out_size, void* d_ws, size_t ws_size,
                              hipStream_t stream) {
    const float* sig = (const float*)d_in[0];
    float* out = (float*)d_out;
    dim3 grid((NFRAMES + TPB - 1) / TPB, BATCH);
    mel_main<<<grid, dim3(TPB), 0, stream>>>(sig, out);
}

// Round 5
// 18.256 us; speedup vs baseline: 1.9561x; 1.0962x over previous
//
#include <hip/hip_runtime.h>

#define NFILT   40
#define FLEN    25      // frame_length = round(0.025*1000)
#define FSTEP   10      // frame_step = round(0.010*1000)
#define BATCH   32
#define SIGLEN  50000
#define NFRAMES 4999    // ceil((50000-25)/10)+1
#define EPSV    2.220446049250313e-16f
#define TPB     128
#define NBLK    40      // ceil(NFRAMES/TPB)
#define SPAN4   1296    // TPB*FSTEP + FLEN - FSTEP = 1295, padded to x4
#define OSTR    41      // LDS transpose stride (odd => bank-spread, conflict-free)

namespace ctab {

constexpr double PI   = 3.14159265358979323846264338327950288;
constexpr double LN10 = 2.30258509299404568401799145468436421;

constexpr double cln(double y) {            // natural log (atanh series)
    double z = (y - 1.0) / (y + 1.0);
    double z2 = z * z, term = z, s = 0.0;
    for (int k = 0; k < 40; ++k) { s += term / (2.0 * k + 1.0); term *= z2; }
    return 2.0 * s;
}
constexpr double cexp(double x) {           // exp, |x| < 0.6
    double s = 1.0, term = 1.0;
    for (int i = 1; i <= 24; ++i) { term *= x / (double)i; s += term; }
    return s;
}
constexpr double ccospi_r(double t) {       // cos(pi*t), t in [0,0.5]
    double x = PI * t, x2 = x * x;
    double s = 1.0, term = 1.0;
    for (int k = 1; k <= 16; ++k) { term *= -x2 / ((2.0 * k - 1.0) * (2.0 * k)); s += term; }
    return s;
}
constexpr double ccospi_m(int m) {          // cos(pi * m / 256)
    int mm = m & 511;
    if (mm > 256) mm = 512 - mm;
    if (mm <= 128) return ccospi_r(mm / 256.0);
    return -ccospi_r((256 - mm) / 256.0);
}

// C[f][d] = (d==0?1:2)/512 * sum_k fbank[f][k] * cos(2*pi*k*d/512), fs=1000
struct CTab {
    float c[NFILT][FLEN];
    constexpr CTab() : c{} {
        double ct[512] = {};
        for (int m = 0; m < 512; ++m) ct[m] = ccospi_m(m);
        double fs = 1000.0;
        double high_mel = 2595.0 * (cln(1.0 + fs / 2.0 / 700.0) / LN10);
        double b[NFILT + 2] = {};
        for (int i = 0; i < NFILT + 2; ++i) {
            double mel = high_mel * (double)i / (double)(NFILT + 1);
            double hz  = 700.0 * (cexp(mel / 2595.0 * LN10) - 1.0);
            b[i] = hz / (fs / 2.0) * 256.0;
        }
        for (int f = 0; f < NFILT; ++f) {
            int left = (int)b[f], center = (int)b[f + 1], right = (int)b[f + 2];
            for (int d = 0; d < FLEN; ++d) {
                double acc = 0.0;
                for (int j = left; j < right; ++j) {
                    double w = (j < center)
                        ? ((double)(j + 1) - b[f])     / (b[f + 1] - b[f])
                        : (b[f + 2] - (double)(j + 1)) / (b[f + 2] - b[f + 1]);
                    acc += w * ct[((j + 1) * d) & 511];
                }
                double v = acc / 512.0;
                if (d) v *= 2.0;
                c[f][d] = (float)v;
            }
        }
    }
};
static constexpr CTab CT{};

} // namespace ctab

__global__ __launch_bounds__(TPB, 3) void mel_main(const float* __restrict__ sig,
                                                   float* __restrict__ out) {
    const int b   = blockIdx.y;
    const int t0  = blockIdx.x * TPB;
    const int tid = threadIdx.x;

    __shared__ float s_sig[SPAN4];
    __shared__ float s_stage[TPB * OSTR];   // 128 frames x 40 filters, padded

    // ---- stage signal window [t0*FSTEP, t0*FSTEP+SPAN) into LDS ----
    const int base = t0 * FSTEP;
    const int rem  = SIGLEN - base;
    const float* sb = sig + (size_t)b * SIGLEN + base;
    #pragma unroll
    for (int i = tid * 4; i < SPAN4; i += TPB * 4) {
        float4 v = make_float4(0.f, 0.f, 0.f, 0.f);
        if (i + 4 <= rem) {
            v = *reinterpret_cast<const float4*>(sb + i);
        } else if (i < rem) {
            v.x = sb[i];
            if (i + 1 < rem) v.y = sb[i + 1];
            if (i + 2 < rem) v.z = sb[i + 2];
        }
        *reinterpret_cast<float4*>(s_sig + i) = v;
    }
    __syncthreads();

    // ---- this frame's 25 samples (zero-padded tail matches reference pad) ----
    float x[FLEN];
    const float* sp = s_sig + tid * FSTEP;
    #pragma unroll
    for (int n = 0; n < FLEN; ++n) x[n] = sp[n];

    // ---- autocorrelation R[d] = sum_n x[n]*x[n+d] ----
    float R[FLEN];
    #pragma unroll
    for (int d = 0; d < FLEN; ++d) {
        float a = 0.f;
        #pragma unroll
        for (int n = 0; n + d < FLEN; ++n) a = fmaf(x[n], x[n + d], a);
        R[d] = a;
    }

    // ---- fb[f] = C[f].R (literal constants); log -> straight to LDS ----
    float* st = s_stage + tid * OSTR;
    #pragma unroll
    for (int f = 0; f < NFILT; ++f) {
        float a = 0.f;
        #pragma unroll
        for (int d = 0; d < FLEN; ++d)
            a = fmaf(ctab::CT.c[f][d], R[d], a);
        if (a < EPSV) a = EPSV;
        st[f] = 6.0205999132796239f * __log2f(a);   // 20*log10
    }
    __syncthreads();

    // ---- coalesced float4 output: 128 frames x 40 = 1280 float4s ----
    const size_t outbase = ((size_t)b * NFRAMES + t0) * NFILT;
    #pragma unroll
    for (int j = 0; j < 10; ++j) {
        int i4 = j * TPB + tid;            // 0..1279, lane-consecutive
        int fr = i4 / 10;
        int fl = i4 - fr * 10;
        if (t0 + fr < NFRAMES) {
            const float* q = s_stage + fr * OSTR + fl * 4;
            float4 v = make_float4(q[0], q[1], q[2], q[3]);
            *reinterpret_cast<float4*>(out + outbase + (size_t)i4 * 4) = v;
        }
    }
}

extern "C" void kernel_launch(void* const* d_in, const int* in_sizes, int n_in,
                              void* d_out, int out_size, void* d_ws, size_t ws_size,
                              hipStream_t stream) {
    const float* sig = (const float*)d_in[0];
    float* out = (float*)d_out;
    dim3 grid(NBLK, BATCH);
    mel_main<<<grid, dim3(TPB), 0, stream>>>(sig, out);
}

// Round 6
// 17.622 us; speedup vs baseline: 2.0264x; 1.0360x over previous
//
#include <hip/hip_runtime.h>

#define NFILT   40
#define FLEN    25      // frame_length = round(0.025*1000)
#define FSTEP   10      // frame_step = round(0.010*1000)
#define BATCH   32
#define SIGLEN  50000
#define NFRAMES 4999    // ceil((50000-25)/10)+1
#define EPSV    2.220446049250313e-16f
#define TPB     64
#define NBLKX   79      // ceil(NFRAMES/64)
#define OSTR    41      // LDS transpose stride (odd => bank-spread, conflict-free)

namespace ctab {

constexpr double PI   = 3.14159265358979323846264338327950288;
constexpr double LN10 = 2.30258509299404568401799145468436421;

constexpr double cln(double y) {            // natural log (atanh series)
    double z = (y - 1.0) / (y + 1.0);
    double z2 = z * z, term = z, s = 0.0;
    for (int k = 0; k < 40; ++k) { s += term / (2.0 * k + 1.0); term *= z2; }
    return 2.0 * s;
}
constexpr double cexp(double x) {           // exp, |x| < 0.6
    double s = 1.0, term = 1.0;
    for (int i = 1; i <= 24; ++i) { term *= x / (double)i; s += term; }
    return s;
}
constexpr double ccospi_r(double t) {       // cos(pi*t), t in [0,0.5]
    double x = PI * t, x2 = x * x;
    double s = 1.0, term = 1.0;
    for (int k = 1; k <= 16; ++k) { term *= -x2 / ((2.0 * k - 1.0) * (2.0 * k)); s += term; }
    return s;
}
constexpr double ccospi_m(int m) {          // cos(pi * m / 256)
    int mm = m & 511;
    if (mm > 256) mm = 512 - mm;
    if (mm <= 128) return ccospi_r(mm / 256.0);
    return -ccospi_r((256 - mm) / 256.0);
}

// C[f][d] = (d==0?1:2)/512 * sum_k fbank[f][k] * cos(2*pi*k*d/512), fs=1000
struct CTab {
    float c[NFILT][FLEN];
    constexpr CTab() : c{} {
        double ct[512] = {};
        for (int m = 0; m < 512; ++m) ct[m] = ccospi_m(m);
        double fs = 1000.0;
        double high_mel = 2595.0 * (cln(1.0 + fs / 2.0 / 700.0) / LN10);
        double b[NFILT + 2] = {};
        for (int i = 0; i < NFILT + 2; ++i) {
            double mel = high_mel * (double)i / (double)(NFILT + 1);
            double hz  = 700.0 * (cexp(mel / 2595.0 * LN10) - 1.0);
            b[i] = hz / (fs / 2.0) * 256.0;
        }
        for (int f = 0; f < NFILT; ++f) {
            int left = (int)b[f], center = (int)b[f + 1], right = (int)b[f + 2];
            for (int d = 0; d < FLEN; ++d) {
                double acc = 0.0;
                for (int j = left; j < right; ++j) {
                    double w = (j < center)
                        ? ((double)(j + 1) - b[f])     / (b[f + 1] - b[f])
                        : (b[f + 2] - (double)(j + 1)) / (b[f + 2] - b[f + 1]);
                    acc += w * ct[((j + 1) * d) & 511];
                }
                double v = acc / 512.0;
                if (d) v *= 2.0;
                c[f][d] = (float)v;
            }
        }
    }
};
static constexpr CTab CT{};

} // namespace ctab

__global__ __launch_bounds__(TPB, 4) void mel_main(const float* __restrict__ sig,
                                                   float* __restrict__ out) {
    const int b    = blockIdx.y;
    const int t0   = blockIdx.x * TPB;
    const int lane = threadIdx.x;
    const int t    = t0 + lane;

    __shared__ float s_stage[TPB * OSTR];   // 64 frames x 40 filters, padded

    // ---- load 25 samples directly from global (8B-aligned float2s) ----
    float x[FLEN];
    if (t < NFRAMES - 1) {                  // full frame, always in-bounds
        const float* gp = sig + (size_t)b * SIGLEN + t * FSTEP;
        #pragma unroll
        for (int q = 0; q < 12; ++q) {
            float2 v = *reinterpret_cast<const float2*>(gp + q * 2);
            x[q * 2] = v.x; x[q * 2 + 1] = v.y;
        }
        x[24] = gp[24];
    } else if (t == NFRAMES - 1) {          // last frame: 20 valid + 5 pad
        const float* gp = sig + (size_t)b * SIGLEN + t * FSTEP;
        #pragma unroll
        for (int q = 0; q < 10; ++q) {
            float2 v = *reinterpret_cast<const float2*>(gp + q * 2);
            x[q * 2] = v.x; x[q * 2 + 1] = v.y;
        }
        #pragma unroll
        for (int n = 20; n < FLEN; ++n) x[n] = 0.f;
    } else {                                // out-of-range thread: dummy work
        #pragma unroll
        for (int n = 0; n < FLEN; ++n) x[n] = 0.f;
    }

    // ---- autocorrelation R[d] = sum_n x[n]*x[n+d] ----
    float R[FLEN];
    #pragma unroll
    for (int d = 0; d < FLEN; ++d) {
        float a = 0.f;
        #pragma unroll
        for (int n = 0; n + d < FLEN; ++n) a = fmaf(x[n], x[n + d], a);
        R[d] = a;
    }

    // ---- fb[f] = C[f].R (literal constants); log -> wave-private LDS ----
    float* st = s_stage + lane * OSTR;
    #pragma unroll
    for (int f = 0; f < NFILT; ++f) {
        float a = 0.f;
        #pragma unroll
        for (int d = 0; d < FLEN; ++d)
            a = fmaf(ctab::CT.c[f][d], R[d], a);
        if (a < EPSV) a = EPSV;
        st[f] = 6.0205999132796239f * __log2f(a);   // 20*log10
    }
    __syncthreads();                        // 1-wave block: ordering only

    // ---- coalesced float4 stores: 64 frames x 40 = 640 float4s ----
    const size_t outbase = ((size_t)b * NFRAMES + t0) * NFILT;
    #pragma unroll
    for (int j = 0; j < 10; ++j) {
        int i4 = j * TPB + lane;            // 0..639, lane-consecutive
        int fr = i4 / 10;
        int fl = i4 - fr * 10;
        if (t0 + fr < NFRAMES) {
            const float* q = s_stage + fr * OSTR + fl * 4;
            float4 v = make_float4(q[0], q[1], q[2], q[3]);
            *reinterpret_cast<float4*>(out + outbase + (size_t)i4 * 4) = v;
        }
    }
}

extern "C" void kernel_launch(void* const* d_in, const int* in_sizes, int n_in,
                              void* d_out, int out_size, void* d_ws, size_t ws_size,
                              hipStream_t stream) {
    const float* sig = (const float*)d_in[0];
    float* out = (float*)d_out;
    dim3 grid(NBLKX, BATCH);
    mel_main<<<grid, dim3(TPB), 0, stream>>>(sig, out);
}

// Round 7
// 17.314 us; speedup vs baseline: 2.0625x; 1.0178x over previous
//
#include <hip/hip_runtime.h>

#define NFILT   40
#define FLEN    25      // frame_length = round(0.025*1000)
#define FSTEP   10      // frame_step = round(0.010*1000)
#define BATCH   32
#define SIGLEN  50000
#define NFRAMES 4999    // ceil((50000-25)/10)+1
#define EPSV    2.220446049250313e-16f
#define TPB     128     // 2 waves per block, both cover the same 64 frames
#define WFR     64      // frames per block
#define NBLKX   79      // ceil(NFRAMES/64)
#define SPAN4   656     // WFR*FSTEP + FLEN - FSTEP = 655, padded to x4
#define OSTR    41      // LDS transpose stride (odd => bank-spread)

namespace ctab {

constexpr double PI   = 3.14159265358979323846264338327950288;
constexpr double LN10 = 2.30258509299404568401799145468436421;

constexpr double cln(double y) {
    double z = (y - 1.0) / (y + 1.0);
    double z2 = z * z, term = z, s = 0.0;
    for (int k = 0; k < 40; ++k) { s += term / (2.0 * k + 1.0); term *= z2; }
    return 2.0 * s;
}
constexpr double cexp(double x) {
    double s = 1.0, term = 1.0;
    for (int i = 1; i <= 24; ++i) { term *= x / (double)i; s += term; }
    return s;
}
constexpr double ccospi_r(double t) {
    double x = PI * t, x2 = x * x;
    double s = 1.0, term = 1.0;
    for (int k = 1; k <= 16; ++k) { term *= -x2 / ((2.0 * k - 1.0) * (2.0 * k)); s += term; }
    return s;
}
constexpr double ccospi_m(int m) {
    int mm = m & 511;
    if (mm > 256) mm = 512 - mm;
    if (mm <= 128) return ccospi_r(mm / 256.0);
    return -ccospi_r((256 - mm) / 256.0);
}

// C[f][d] = (d==0?1:2)/512 * sum_k fbank[f][k] * cos(2*pi*k*d/512), fs=1000
struct CTab {
    float c[NFILT][FLEN];
    constexpr CTab() : c{} {
        double ct[512] = {};
        for (int m = 0; m < 512; ++m) ct[m] = ccospi_m(m);
        double fs = 1000.0;
        double high_mel = 2595.0 * (cln(1.0 + fs / 2.0 / 700.0) / LN10);
        double b[NFILT + 2] = {};
        for (int i = 0; i < NFILT + 2; ++i) {
            double mel = high_mel * (double)i / (double)(NFILT + 1);
            double hz  = 700.0 * (cexp(mel / 2595.0 * LN10) - 1.0);
            b[i] = hz / (fs / 2.0) * 256.0;
        }
        for (int f = 0; f < NFILT; ++f) {
            int left = (int)b[f], center = (int)b[f + 1], right = (int)b[f + 2];
            for (int d = 0; d < FLEN; ++d) {
                double acc = 0.0;
                for (int j = left; j < right; ++j) {
                    double w = (j < center)
                        ? ((double)(j + 1) - b[f])     / (b[f + 1] - b[f])
                        : (b[f + 2] - (double)(j + 1)) / (b[f + 2] - b[f + 1]);
                    acc += w * ct[((j + 1) * d) & 511];
                }
                double v = acc / 512.0;
                if (d) v *= 2.0;
                c[f][d] = (float)v;
            }
        }
    }
};
static constexpr CTab CT{};

} // namespace ctab

__global__ __launch_bounds__(TPB, 4) void mel_main(const float* __restrict__ sig,
                                                   float* __restrict__ out) {
    const int b    = blockIdx.y;
    const int t0   = blockIdx.x * WFR;
    const int tid  = threadIdx.x;
    const int wave = tid >> 6;              // 0 or 1 (filter half)
    const int lane = tid & 63;              // frame within block

    __shared__ float s_sig[SPAN4];
    __shared__ float s_stage[WFR * OSTR];   // 64 frames x 40 filters, padded

    // ---- cooperative stage of 655-sample window (fully coalesced) ----
    const int base = t0 * FSTEP;
    const int rem  = SIGLEN - base;
    const float* sb = sig + (size_t)b * SIGLEN + base;
    #pragma unroll
    for (int i = tid * 4; i < SPAN4; i += TPB * 4) {
        float4 v = make_float4(0.f, 0.f, 0.f, 0.f);
        if (i + 4 <= rem) {
            v = *reinterpret_cast<const float4*>(sb + i);
        } else if (i < rem) {
            v.x = sb[i];
            if (i + 1 < rem) v.y = sb[i + 1];
            if (i + 2 < rem) v.z = sb[i + 2];
        }
        *reinterpret_cast<float4*>(s_sig + i) = v;
    }
    __syncthreads();

    // ---- both waves: this lane's frame samples + autocorrelation ----
    float x[FLEN];
    const float* sp = s_sig + lane * FSTEP;
    #pragma unroll
    for (int n = 0; n < FLEN; ++n) x[n] = sp[n];

    float R[FLEN];
    #pragma unroll
    for (int d = 0; d < FLEN; ++d) {
        float a = 0.f;
        #pragma unroll
        for (int n = 0; n + d < FLEN; ++n) a = fmaf(x[n], x[n + d], a);
        R[d] = a;
    }

    // ---- 20 filters per wave; C as instruction literals (compile-time f) ----
    float* st = s_stage + lane * OSTR + wave * (NFILT / 2);
    if (wave == 0) {
        #pragma unroll
        for (int f = 0; f < NFILT / 2; ++f) {
            float a = 0.f;
            #pragma unroll
            for (int d = 0; d < FLEN; ++d)
                a = fmaf(ctab::CT.c[f][d], R[d], a);
            if (a < EPSV) a = EPSV;
            st[f] = 6.0205999132796239f * __log2f(a);
        }
    } else {
        #pragma unroll
        for (int f = 0; f < NFILT / 2; ++f) {
            float a = 0.f;
            #pragma unroll
            for (int d = 0; d < FLEN; ++d)
                a = fmaf(ctab::CT.c[NFILT / 2 + f][d], R[d], a);
            if (a < EPSV) a = EPSV;
            st[f] = 6.0205999132796239f * __log2f(a);
        }
    }
    __syncthreads();

    // ---- coalesced float4 stores: 64 frames x 40 = 640 float4s, 5/thread ----
    const size_t outbase = ((size_t)b * NFRAMES + t0) * NFILT;
    #pragma unroll
    for (int j = 0; j < 5; ++j) {
        int i4 = j * TPB + tid;             // 0..639, lane-consecutive
        int fr = i4 / 10;
        int fl = i4 - fr * 10;
        if (t0 + fr < NFRAMES) {
            const float* q = s_stage + fr * OSTR + fl * 4;
            float4 v = make_float4(q[0], q[1], q[2], q[3]);
            *reinterpret_cast<float4*>(out + outbase + (size_t)i4 * 4) = v;
        }
    }
}

extern "C" void kernel_launch(void* const* d_in, const int* in_sizes, int n_in,
                              void* d_out, int out_size, void* d_ws, size_t ws_size,
                              hipStream_t stream) {
    const float* sig = (const float*)d_in[0];
    float* out = (float*)d_out;
    dim3 grid(NBLKX, BATCH);
    mel_main<<<grid, dim3(TPB), 0, stream>>>(sig, out);
}